// Round 5
// baseline (73.856 us; speedup 1.0000x reference)
//
#include <hip/hip_runtime.h>

constexpr int N = 512;   // number of samples
constexpr int D = 256;   // feature dim
#define MARGIN 1.0f

// Final reduction state in module-scope globals (workspace is poison-filled
// every iteration). All cross-block communication goes through device-scope
// atomics (coherent at the home L2 slice on CDNA) — NO __threadfence, whose
// dirty-L2 writeback cost ~15 us in round 2. Self re-arming across replays.
__device__ float g_sum = 0.f;
__device__ float g_cnt = 0.f;
__device__ int g_ticket = 0;

// 16-lane (DPP "row") sum reduction on the VALU pipe: 4 dependent v_add
// with row_shr (~4cy each) instead of 4 ds_bpermute (~30cy each).
// row_shr:N reads lane i-N => the complete row sum lands in the LAST
// lane of each 16-group (sub==15).
__device__ __forceinline__ float dpp_add16(float v) {
  v += __int_as_float(__builtin_amdgcn_update_dpp(
      0, __float_as_int(v), 0x118, 0xF, 0xF, true));
  v += __int_as_float(__builtin_amdgcn_update_dpp(
      0, __float_as_int(v), 0x114, 0xF, 0xF, true));
  v += __int_as_float(__builtin_amdgcn_update_dpp(
      0, __float_as_int(v), 0x112, 0xF, 0xF, true));
  v += __int_as_float(__builtin_amdgcn_update_dpp(
      0, __float_as_int(v), 0x111, 0xF, 0xF, true));
  return v;
}

// Block b (1024 threads = 16 waves) owns anchors i0=2b, i1=2b+1; each row
// is loaded once for both anchors. 256 blocks -> 1 block/CU. Inner loop is
// software-pipelined DEPTH 2 (rows it+1 and it+2 in flight) because the
// post-poison memory system shows inflated L2/HBM latency that depth 1
// did not cover (round-4 evidence: depth-1 prefetch gained only 1.1 us).
#define ACC(S, A, B)                                                   \
  { float ex = A.x - B.x, ey = A.y - B.y, ez = A.z - B.z,              \
          ew = A.w - B.w;                                              \
    S += ex * ex + ey * ey + ez * ez + ew * ew; }

__global__ __launch_bounds__(1024, 4) void triplet_fused(
    const float* __restrict__ x, const int* __restrict__ tgt,
    float* __restrict__ out) {
  __shared__ __align__(16) float m0[N], m1[N];  // dist rows, +INF at positives
  __shared__ float cl0[N], cl1[N];              // compacted c = d_ap + margin
  __shared__ int ts[N];                         // targets, staged once
  __shared__ int nv0, nv1;
  __shared__ float wred[32];                    // 16 waves x {sum | cnt}

  const int b = blockIdx.x;
  const int i0 = 2 * b, i1 = 2 * b + 1;
  const int tid = threadIdx.x;                  // 1024 threads = 16 waves
  const int wave = tid >> 6, lane = tid & 63;
  const int sub = lane & 15, rg = lane >> 4;    // chunk-in-row, row-in-group

  if (tid == 0) { nv0 = 0; nv1 = 0; }
  if (tid < N) ts[tid] = tgt[tid];              // one coalesced pass

  // both anchors' row fragments, loop-invariant registers
  const float4* xa = (const float4*)(x + (size_t)i0 * D);
  const float4* xc = (const float4*)(x + (size_t)i1 * D);
  float4 a0 = xa[sub], a1 = xa[16 + sub], a2 = xa[32 + sub], a3 = xa[48 + sub];
  float4 c0 = xc[sub], c1 = xc[16 + sub], c2 = xc[32 + sub], c3 = xc[48 + sub];
  __syncthreads();                              // nv zeroed, ts ready
  const int t0 = ts[i0], t1 = ts[i1];

  // Wave w covers rows [w*32, w*32+32): 4 rows/iter (one per 16-lane group).
  // Per-block rotation decorrelates the blocks' L2 streams.
  const int rot = (b * 171) & (N - 1);
  const int rbase = wave * 32 + rg;

  // prologue: rows for iterations 0 and 1 in flight
  int rc = (rbase + rot) & (N - 1);
  int rn = (rbase + 4 + rot) & (N - 1);
  const float4* xr0 = (const float4*)(x + (size_t)rc * D);
  float4 b0 = xr0[sub], b1 = xr0[16 + sub], b2 = xr0[32 + sub],
         b3 = xr0[48 + sub];
  const float4* xr1 = (const float4*)(x + (size_t)rn * D);
  float4 n0 = xr1[sub], n1 = xr1[16 + sub], n2 = xr1[32 + sub],
         n3 = xr1[48 + sub];

  #pragma unroll 2
  for (int it = 0; it < 8; ++it) {
    // issue iteration it+2's loads (wraps to warm rows at the tail)
    const int rp = (rbase + (((it + 2) & 7) << 2) + rot) & (N - 1);
    const float4* xp = (const float4*)(x + (size_t)rp * D);
    float4 p0 = xp[sub], p1 = xp[16 + sub], p2 = xp[32 + sub],
           p3 = xp[48 + sub];

    float sa = 0.f, sb = 0.f;                   // d^2 partials, both anchors
    ACC(sa, a0, b0); ACC(sa, a1, b1); ACC(sa, a2, b2); ACC(sa, a3, b3);
    ACC(sb, c0, b0); ACC(sb, c1, b1); ACC(sb, c2, b2); ACC(sb, c3, b3);
    sa = dpp_add16(sa);                         // VALU-pipe 16-lane reduce
    sb = dpp_add16(sb);
    if (sub == 15) {                            // row sum lands in LAST lane
      const int tj = ts[rc];
      float da = sqrtf(fmaxf(sa, 1e-16f));
      float db = sqrtf(fmaxf(sb, 1e-16f));
      m0[rc] = (tj != t0) ? da : __builtin_inff();
      m1[rc] = (tj != t1) ? db : __builtin_inff();
      if (tj == t0 && rc != i0) { int s = atomicAdd(&nv0, 1); cl0[s] = da + MARGIN; }
      if (tj == t1 && rc != i1) { int s = atomicAdd(&nv1, 1); cl1[s] = db + MARGIN; }
    }
    // rotate the depth-2 pipeline
    b0 = n0; b1 = n1; b2 = n2; b3 = n3;
    n0 = p0; n1 = p1; n2 = p2; n3 = p3;
    rc = rn; rn = rp;
  }
  __syncthreads();

  // triplet phase: thread pair (tid, tid+512) shares element e=tid&511 and
  // splits each clist between them (v = half, half+2, ...)
  float sum = 0.f, cnt = 0.f;
  const int e = tid & 511, half = tid >> 9;
  const float mk0 = m0[e], mk1 = m1[e];
  const int nn0 = nv0, nn1 = nv1;
  for (int v = half; v < nn0; v += 2) {
    float a = cl0[v] - mk0;                     // cl0[v] is LDS broadcast
    sum += fmaxf(a, 0.f);
    cnt += (a > 1e-16f ? 1.f : 0.f);
  }
  for (int v = half; v < nn1; v += 2) {
    float a = cl1[v] - mk1;
    sum += fmaxf(a, 0.f);
    cnt += (a > 1e-16f ? 1.f : 0.f);
  }

  // block reduction over 16 waves
  #pragma unroll
  for (int off = 32; off > 0; off >>= 1) {
    sum += __shfl_down(sum, off);
    cnt += __shfl_down(cnt, off);
  }
  if (lane == 0) { wred[wave] = sum; wred[16 + wave] = cnt; }
  __syncthreads();

  // single-dispatch finalize: device-scope atomics only (no threadfence).
  // cnt is integer-valued (<2^24, exact in fp32); sum reassociation error
  // ~1e-5 relative, far inside the harness threshold.
  if (tid == 0) {
    float s = 0.f, c = 0.f;
    #pragma unroll
    for (int w = 0; w < 16; ++w) { s += wred[w]; c += wred[16 + w]; }
    atomicAdd(&g_sum, s);
    atomicAdd(&g_cnt, c);
    // order: my sum/cnt RMWs must complete (at the coherent point) before
    // my ticket increment is visible. One-wave vmcnt drain, NOT a fence.
    asm volatile("s_waitcnt vmcnt(0)" ::: "memory");
    const int old = atomicAdd(&g_ticket, 1);
    if (old == N / 2 - 1) {                     // last block: all adds done
      const float tsum = atomicAdd(&g_sum, 0.f);   // coherent read
      const float tcnt = atomicAdd(&g_cnt, 0.f);
      out[0] = tsum / (tcnt + 1e-16f);
      // re-arm for the next graph replay (next launch is stream-ordered
      // after all of this kernel's memory ops)
      atomicExch(&g_sum, 0.f);
      atomicExch(&g_cnt, 0.f);
      atomicExch(&g_ticket, 0);
    }
  }
}

extern "C" void kernel_launch(void* const* d_in, const int* in_sizes, int n_in,
                              void* d_out, int out_size, void* d_ws, size_t ws_size,
                              hipStream_t stream) {
  const float* x = (const float*)d_in[0];   // [512, 256] fp32
  const int* tgt = (const int*)d_in[1];     // [512] int32
  float* out = (float*)d_out;               // scalar fp32
  (void)d_ws; (void)ws_size;                // workspace unused; reduction
                                            // state lives in device globals

  triplet_fused<<<N / 2, 1024, 0, stream>>>(x, tgt, out);
}

// Round 6
// 65.988 us; speedup vs baseline: 1.1192x; 1.1192x over previous
//
#include <hip/hip_runtime.h>

constexpr int N = 512;   // number of samples
constexpr int D = 256;   // feature dim
#define MARGIN 1.0f

// 16-lane (DPP "row") sum reduction on the VALU pipe: 4 dependent v_add
// with row_shr (~4cy each) instead of 4 ds_bpermute (~30cy each).
// row_shr:N reads lane i-N => the complete row sum lands in the LAST
// lane of each 16-group (sub==15).
__device__ __forceinline__ float dpp_add16(float v) {
  v += __int_as_float(__builtin_amdgcn_update_dpp(
      0, __float_as_int(v), 0x118, 0xF, 0xF, true));
  v += __int_as_float(__builtin_amdgcn_update_dpp(
      0, __float_as_int(v), 0x114, 0xF, 0xF, true));
  v += __int_as_float(__builtin_amdgcn_update_dpp(
      0, __float_as_int(v), 0x112, 0xF, 0xF, true));
  v += __int_as_float(__builtin_amdgcn_update_dpp(
      0, __float_as_int(v), 0x111, 0xF, 0xF, true));
  return v;
}

// Two-dispatch skeleton (verified fastest: single-dispatch ticket finalize
// costs +9us from contended same-line atomics — R2/R5 both measured it).
// Block b (1024 threads = 16 waves) owns anchors i0=2b, i1=2b+1; each row
// is loaded once for both anchors. 256 blocks -> 1 block/CU. Inner loop
// software-pipelined depth 2 (rows it+1, it+2 in flight).
#define ACC(S, A, B)                                                   \
  { float ex = A.x - B.x, ey = A.y - B.y, ez = A.z - B.z,              \
          ew = A.w - B.w;                                              \
    S += ex * ex + ey * ey + ez * ez + ew * ew; }

__global__ __launch_bounds__(1024, 4) void triplet_fused(
    const float* __restrict__ x, const int* __restrict__ tgt,
    float* __restrict__ part) {
  __shared__ __align__(16) float m0[N], m1[N];  // dist rows, +INF at positives
  __shared__ float cl0[N], cl1[N];              // compacted c = d_ap + margin
  __shared__ int ts[N];                         // targets, staged once
  __shared__ int nv0, nv1;
  __shared__ float wred[32];                    // 16 waves x {sum | cnt}

  const int b = blockIdx.x;
  const int i0 = 2 * b, i1 = 2 * b + 1;
  const int tid = threadIdx.x;                  // 1024 threads = 16 waves
  const int wave = tid >> 6, lane = tid & 63;
  const int sub = lane & 15, rg = lane >> 4;    // chunk-in-row, row-in-group

  if (tid == 0) { nv0 = 0; nv1 = 0; }
  if (tid < N) ts[tid] = tgt[tid];              // one coalesced pass

  // both anchors' row fragments, loop-invariant registers
  const float4* xa = (const float4*)(x + (size_t)i0 * D);
  const float4* xc = (const float4*)(x + (size_t)i1 * D);
  float4 a0 = xa[sub], a1 = xa[16 + sub], a2 = xa[32 + sub], a3 = xa[48 + sub];
  float4 c0 = xc[sub], c1 = xc[16 + sub], c2 = xc[32 + sub], c3 = xc[48 + sub];
  __syncthreads();                              // nv zeroed, ts ready
  const int t0 = ts[i0], t1 = ts[i1];

  // Wave w covers rows [w*32, w*32+32): 4 rows/iter (one per 16-lane group).
  // Per-block rotation decorrelates the blocks' L2 streams.
  const int rot = (b * 171) & (N - 1);
  const int rbase = wave * 32 + rg;

  // prologue: rows for iterations 0 and 1 in flight
  int rc = (rbase + rot) & (N - 1);
  int rn = (rbase + 4 + rot) & (N - 1);
  const float4* xr0 = (const float4*)(x + (size_t)rc * D);
  float4 b0 = xr0[sub], b1 = xr0[16 + sub], b2 = xr0[32 + sub],
         b3 = xr0[48 + sub];
  const float4* xr1 = (const float4*)(x + (size_t)rn * D);
  float4 n0 = xr1[sub], n1 = xr1[16 + sub], n2 = xr1[32 + sub],
         n3 = xr1[48 + sub];

  #pragma unroll 2
  for (int it = 0; it < 8; ++it) {
    // issue iteration it+2's loads (wraps to warm rows at the tail)
    const int rp = (rbase + (((it + 2) & 7) << 2) + rot) & (N - 1);
    const float4* xp = (const float4*)(x + (size_t)rp * D);
    float4 p0 = xp[sub], p1 = xp[16 + sub], p2 = xp[32 + sub],
           p3 = xp[48 + sub];

    const int tj = ts[rc];                      // hoisted: LDS latency hides
                                                // under the ACC+DPP chain
    float sa = 0.f, sb = 0.f;                   // d^2 partials, both anchors
    ACC(sa, a0, b0); ACC(sa, a1, b1); ACC(sa, a2, b2); ACC(sa, a3, b3);
    ACC(sb, c0, b0); ACC(sb, c1, b1); ACC(sb, c2, b2); ACC(sb, c3, b3);
    sa = dpp_add16(sa);                         // VALU-pipe 16-lane reduce
    sb = dpp_add16(sb);
    if (sub == 15) {                            // row sum lands in LAST lane
      float da = sqrtf(fmaxf(sa, 1e-16f));
      float db = sqrtf(fmaxf(sb, 1e-16f));
      m0[rc] = (tj != t0) ? da : __builtin_inff();
      m1[rc] = (tj != t1) ? db : __builtin_inff();
      if (tj == t0 && rc != i0) { int s = atomicAdd(&nv0, 1); cl0[s] = da + MARGIN; }
      if (tj == t1 && rc != i1) { int s = atomicAdd(&nv1, 1); cl1[s] = db + MARGIN; }
    }
    // rotate the depth-2 pipeline
    b0 = n0; b1 = n1; b2 = n2; b3 = n3;
    n0 = p0; n1 = p1; n2 = p2; n3 = p3;
    rc = rn; rn = rp;
  }
  __syncthreads();

  // triplet phase: thread pair (tid, tid+512) shares element e=tid&511 and
  // splits each clist between them (v = half, half+2, ...)
  float sum = 0.f, cnt = 0.f;
  const int e = tid & 511, half = tid >> 9;
  const float mk0 = m0[e], mk1 = m1[e];
  const int nn0 = nv0, nn1 = nv1;
  for (int v = half; v < nn0; v += 2) {
    float a = cl0[v] - mk0;                     // cl0[v] is LDS broadcast
    sum += fmaxf(a, 0.f);
    cnt += (a > 1e-16f ? 1.f : 0.f);
  }
  for (int v = half; v < nn1; v += 2) {
    float a = cl1[v] - mk1;
    sum += fmaxf(a, 0.f);
    cnt += (a > 1e-16f ? 1.f : 0.f);
  }

  // block reduction over 16 waves, one partial pair per block
  #pragma unroll
  for (int off = 32; off > 0; off >>= 1) {
    sum += __shfl_down(sum, off);
    cnt += __shfl_down(cnt, off);
  }
  if (lane == 0) { wred[wave] = sum; wred[16 + wave] = cnt; }
  __syncthreads();
  if (tid == 0) {
    float s = 0.f, c = 0.f;
    #pragma unroll
    for (int w = 0; w < 16; ++w) { s += wred[w]; c += wred[16 + w]; }
    part[2 * b] = s;
    part[2 * b + 1] = c;
  }
}

// Reduce 256 (sum,cnt) partials and divide.
__global__ __launch_bounds__(256) void triplet_finalize(
    const float* __restrict__ part, float* __restrict__ out) {
  __shared__ float wred[8];
  const int tid = threadIdx.x;
  float s = part[2 * tid], c = part[2 * tid + 1];
  #pragma unroll
  for (int off = 32; off > 0; off >>= 1) {
    s += __shfl_down(s, off);
    c += __shfl_down(c, off);
  }
  int wave = tid >> 6, lane = tid & 63;
  if (lane == 0) { wred[wave] = s; wred[4 + wave] = c; }
  __syncthreads();
  if (tid == 0) {
    float ts = wred[0] + wred[1] + wred[2] + wred[3];
    float tc = wred[4] + wred[5] + wred[6] + wred[7];
    out[0] = ts / (tc + 1e-16f);
  }
}

extern "C" void kernel_launch(void* const* d_in, const int* in_sizes, int n_in,
                              void* d_out, int out_size, void* d_ws, size_t ws_size,
                              hipStream_t stream) {
  const float* x = (const float*)d_in[0];   // [512, 256] fp32
  const int* tgt = (const int*)d_in[1];     // [512] int32
  float* out = (float*)d_out;               // scalar fp32
  float* part = (float*)d_ws;               // 256 x {sum, cnt} partials

  triplet_fused<<<N / 2, 1024, 0, stream>>>(x, tgt, part);
  triplet_finalize<<<1, 256, 0, stream>>>(part, out);
}